// Round 3
// baseline (587.303 us; speedup 1.0000x reference)
//
#include <hip/hip_runtime.h>
#include <stdint.h>

#define GLOBAL_AS __attribute__((address_space(1)))
#define LDS_AS __attribute__((address_space(3)))

typedef float f32x4 __attribute__((ext_vector_type(4)));
typedef short bf16x8 __attribute__((ext_vector_type(8)));

static __device__ __forceinline__ unsigned short f2b(float f) {
  union { float f; unsigned u; } v; v.f = f;
  return (unsigned short)((v.u + 0x7FFFu + ((v.u >> 16) & 1u)) >> 16);
}

static __device__ __forceinline__ void async16(const void* g, void* l) {
  __builtin_amdgcn_global_load_lds((const GLOBAL_AS unsigned int*)g,
                                   (LDS_AS unsigned int*)l, 16, 0, 0);
}

#define BAR() do { __builtin_amdgcn_s_barrier(); __builtin_amdgcn_sched_barrier(0); } while (0)

// ---------------- fused prep: cast_x | rope table | 4x transpose-cast ----------------
__global__ void prep_kernel(const float* __restrict__ x,
                            const float* __restrict__ Wq, const float* __restrict__ Wk,
                            const float* __restrict__ Wv, const float* __restrict__ Wo,
                            unsigned short* __restrict__ xb,
                            unsigned short* __restrict__ WcatT, unsigned short* __restrict__ WoT,
                            float* __restrict__ cosT, float* __restrict__ sinT) {
  __shared__ float tile[32][33];
  const int bid = blockIdx.x;
  const int tid = threadIdx.x;
  if (bid < 16384) {
    const int i = bid * 256 + tid;
    float4 v = ((const float4*)x)[i];
    ushort4 o;
    o.x = f2b(v.x); o.y = f2b(v.y); o.z = f2b(v.z); o.w = f2b(v.w);
    ((ushort4*)xb)[i] = o;
  } else if (bid < 16384 + 512) {
    const int idx = (bid - 16384) * 256 + tid;
    const int s = idx >> 5, j = idx & 31;
    float freq = expf(-((float)(2 * j) * (1.0f / 64.0f)) * 9.210340371976184f);
    float ang = (float)s * freq;
    float sn, cs;
    sincosf(ang, &sn, &cs);
    cosT[idx] = cs;
    sinT[idx] = sn;
  } else {
    const int t = bid - 16896;
    const int mat = t >> 10;
    const int r = t & 1023;
    const int k0 = (r & 31) * 32, n0 = (r >> 5) * 32;
    const float* W = (mat == 0) ? Wq : (mat == 1) ? Wk : (mat == 2) ? Wv : Wo;
    unsigned short* WT = (mat < 3) ? (WcatT + (size_t)mat * 1024 * 1024) : WoT;
    const int tx = tid & 31, ty = tid >> 5;
    #pragma unroll
    for (int i = 0; i < 4; i++)
      tile[ty + i * 8][tx] = W[(size_t)(k0 + ty + i * 8) * 1024 + n0 + tx];
    __syncthreads();
    #pragma unroll
    for (int i = 0; i < 4; i++)
      WT[(size_t)(n0 + ty + i * 8) * 1024 + k0 + tx] = f2b(tile[tx][ty + i * 8]);
  }
}

// ---------------- 256x256x(K=1024) 8-phase core, software-pipelined ds_reads ----------------
// 512 thr / 8 waves (2M x 4N), wave tile 128x64, acc[8][4]. BK=64.
// LDS: 2 dbuf x {A0,A1,B0,B1} half-tiles of 128x64 bf16 (16KB each) = 128KB.
// Key change vs round 2: every ds_read is issued ONE FULL MFMA CLUSTER before its consumer,
// so LDS drain overlaps the matrix pipe instead of serializing with it:
//   ph1: read aq1(t)        -> consumed MFMA3 (ph3)
//   ph3: read b01n/b23n(t+1)-> consumed next tile MFMA1/MFMA2
//   ph4: read aq0(t+1)      -> consumed next tile MFMA1 (aq0 dead after ph2: read in place)
// Staging stagger (A(t+1)->nxt in ph1/ph2, B(t+2)->cur.B in ph3/ph4) keeps loads in flight
// across barriers. vmcnt waits are placed ONE PHASE BEFORE the dependent reads so a barrier
// separates every wave's counted drain from cross-wave-staged data reads:
//   ph2: vmcnt(4) drains B(t+1) (read in ph3); ph3: vmcnt(2) drains A(t+1) (read in ph4).
// Per-wave vmem issue order per tile: A0(t+1), A1(t+1), B0(t+2), B1(t+2) = 8 loads;
// entry invariant: 4 outstanding (B(t+1)). Tails: t=14 -> vmcnt(4)/vmcnt(0); t=15 none.
__device__ __forceinline__ void gemm256_core(const unsigned short* __restrict__ Ag,
                                             const unsigned short* __restrict__ Bg,
                                             int m0, int n0, char* lds, f32x4 (&acc)[8][4]) {
  const int tid = threadIdx.x;
  const int lane = tid & 63;
  const int lrow = lane & 15;
  const int quad = lane >> 4;
  const int wave = tid >> 6;
  const int wm = wave >> 2;
  const int wn = wave & 3;

  const unsigned short* Ar0 = Ag + (size_t)m0 * 1024;
  const unsigned short* Ar1 = Ag + (size_t)(m0 + 128) * 1024;
  const unsigned short* Br0 = Bg + (size_t)n0 * 1024;
  const unsigned short* Br1 = Bg + (size_t)(n0 + 128) * 1024;

  // one half-tile = 128 rows x 64 cols bf16 = 1024 slots of 16B; 2 loads/thread.
  // source-side chunk swizzle (ch ^ row&7), linear LDS dest: LDS[row][c] = G[row][c^(row&7)].
  auto stage = [&](const unsigned short* src, char* dst) {
    #pragma unroll
    for (int l = 0; l < 2; ++l) {
      const int slot = l * 512 + tid;
      const int row = slot >> 3;
      const int ch = (slot & 7) ^ (row & 7);
      async16(src + (size_t)row * 1024 + ch * 8, dst + slot * 16);
    }
  };

  const int br0 = (wn & 1) * 64;

  // prologue: tile0 all 4 halves + tile1 B halves. 12 loads; vmcnt(4) -> A(0),B(0) landed.
  stage(Ar0, lds);
  stage(Ar1, lds + 16384);
  stage(Br0, lds + 32768);
  stage(Br1, lds + 49152);
  stage(Br0 + 64, lds + 65536 + 32768);
  stage(Br1 + 64, lds + 65536 + 49152);
  asm volatile("s_waitcnt vmcnt(4)" ::: "memory");
  BAR();  // cross-wave: all waves drained their share of A(0)/B(0)

  bf16x8 aq0[4][2], aq1[4][2], b01[2][2], b23[2][2], b01n[2][2], b23n[2][2];

  {
    const char* aB = lds + wm * 16384;
    const char* bB = lds + 32768 + (wn >> 1) * 16384;
    #pragma unroll
    for (int mt = 0; mt < 4; ++mt)
      #pragma unroll
      for (int kk = 0; kk < 2; ++kk) {
        const int r = mt * 16 + lrow;
        const int kc = kk * 4 + quad;
        aq0[mt][kk] = *(const bf16x8*)(aB + r * 128 + ((kc ^ (r & 7)) << 4));
      }
    #pragma unroll
    for (int nt = 0; nt < 2; ++nt)
      #pragma unroll
      for (int kk = 0; kk < 2; ++kk) {
        const int kc = kk * 4 + quad;
        const int r1 = br0 + nt * 16 + lrow;
        b01[nt][kk] = *(const bf16x8*)(bB + r1 * 128 + ((kc ^ (r1 & 7)) << 4));
        const int r2 = br0 + (nt + 2) * 16 + lrow;
        b23[nt][kk] = *(const bf16x8*)(bB + r2 * 128 + ((kc ^ (r2 & 7)) << 4));
      }
  }

  #pragma unroll 1
  for (int t = 0; t < 16; ++t) {
    const int kt = t * 64;
    char* cur = lds + ((t & 1) << 16);
    char* nxt = lds + (((t + 1) & 1) << 16);
    const char* aB  = cur + wm * 16384;
    const char* aBn = nxt + wm * 16384;
    const char* bBn = nxt + 32768 + (wn >> 1) * 16384;

    // ---- ph1: stage A0(t+1)->nxt; read aq1(t); MFMA1 = aq0 x b01 -> acc[0..3][0..1]
    if (t < 15) stage(Ar0 + kt + 64, nxt);
    #pragma unroll
    for (int mt = 0; mt < 4; ++mt)
      #pragma unroll
      for (int kk = 0; kk < 2; ++kk) {
        const int r = 64 + mt * 16 + lrow;
        const int kc = kk * 4 + quad;
        aq1[mt][kk] = *(const bf16x8*)(aB + r * 128 + ((kc ^ (r & 7)) << 4));
      }
    BAR();
    __builtin_amdgcn_s_setprio(1);
    #pragma unroll
    for (int kk = 0; kk < 2; ++kk)
      #pragma unroll
      for (int mt = 0; mt < 4; ++mt)
        #pragma unroll
        for (int nt = 0; nt < 2; ++nt)
          acc[mt][nt] = __builtin_amdgcn_mfma_f32_16x16x32_bf16(aq0[mt][kk], b01[nt][kk], acc[mt][nt], 0, 0, 0);
    __builtin_amdgcn_s_setprio(0);
    BAR();

    // ---- ph2: stage A1(t+1)->nxt; vmcnt(4) drains B(t+1); MFMA2 = aq0 x b23 -> acc[0..3][2..3]
    if (t < 15) stage(Ar1 + kt + 64, nxt + 16384);
    if (t < 15) { asm volatile("s_waitcnt vmcnt(4)" ::: "memory"); }
    BAR();
    __builtin_amdgcn_s_setprio(1);
    #pragma unroll
    for (int kk = 0; kk < 2; ++kk)
      #pragma unroll
      for (int mt = 0; mt < 4; ++mt)
        #pragma unroll
        for (int nt = 0; nt < 2; ++nt)
          acc[mt][nt + 2] = __builtin_amdgcn_mfma_f32_16x16x32_bf16(aq0[mt][kk], b23[nt][kk], acc[mt][nt + 2], 0, 0, 0);
    __builtin_amdgcn_s_setprio(0);
    BAR();

    // ---- ph3: stage B0(t+2)->cur.B0; vmcnt(2) drains A(t+1); read b01n/b23n(t+1) from nxt
    //      (B(t+1) landed: every wave's vmcnt(4) + 2 barriers ago); MFMA3 = aq1 x b23
    if (t < 14) stage(Br0 + kt + 128, cur + 32768);
    if (t < 14)      { asm volatile("s_waitcnt vmcnt(2)" ::: "memory"); }
    else if (t == 14){ asm volatile("s_waitcnt vmcnt(0)" ::: "memory"); }
    if (t < 15) {
      #pragma unroll
      for (int nt = 0; nt < 2; ++nt)
        #pragma unroll
        for (int kk = 0; kk < 2; ++kk) {
          const int kc = kk * 4 + quad;
          const int r1 = br0 + nt * 16 + lrow;
          b01n[nt][kk] = *(const bf16x8*)(bBn + r1 * 128 + ((kc ^ (r1 & 7)) << 4));
          const int r2 = br0 + (nt + 2) * 16 + lrow;
          b23n[nt][kk] = *(const bf16x8*)(bBn + r2 * 128 + ((kc ^ (r2 & 7)) << 4));
        }
    }
    BAR();
    __builtin_amdgcn_s_setprio(1);
    #pragma unroll
    for (int kk = 0; kk < 2; ++kk)
      #pragma unroll
      for (int mt = 0; mt < 4; ++mt)
        #pragma unroll
        for (int nt = 0; nt < 2; ++nt)
          acc[mt + 4][nt + 2] = __builtin_amdgcn_mfma_f32_16x16x32_bf16(aq1[mt][kk], b23[nt][kk], acc[mt + 4][nt + 2], 0, 0, 0);
    __builtin_amdgcn_s_setprio(0);
    BAR();

    // ---- ph4: stage B1(t+2)->cur.B1; read aq0(t+1) from nxt (A(t+1) landed: ph3 vmcnt + barrier);
    //      MFMA4 = aq1 x b01 -> acc[4..7][0..1]; boundary barrier.
    if (t < 14) stage(Br1 + kt + 128, cur + 49152);
    if (t < 15) {
      #pragma unroll
      for (int mt = 0; mt < 4; ++mt)
        #pragma unroll
        for (int kk = 0; kk < 2; ++kk) {
          const int r = mt * 16 + lrow;
          const int kc = kk * 4 + quad;
          aq0[mt][kk] = *(const bf16x8*)(aBn + r * 128 + ((kc ^ (r & 7)) << 4));
        }
    }
    BAR();
    __builtin_amdgcn_s_setprio(1);
    #pragma unroll
    for (int kk = 0; kk < 2; ++kk)
      #pragma unroll
      for (int mt = 0; mt < 4; ++mt)
        #pragma unroll
        for (int nt = 0; nt < 2; ++nt)
          acc[mt + 4][nt] = __builtin_amdgcn_mfma_f32_16x16x32_bf16(aq1[mt][kk], b01[nt][kk], acc[mt + 4][nt], 0, 0, 0);
    __builtin_amdgcn_s_setprio(0);
    BAR();

    // rotate B fragments (aq0 was read in place)
    #pragma unroll
    for (int nt = 0; nt < 2; ++nt)
      #pragma unroll
      for (int kk = 0; kk < 2; ++kk) {
        b01[nt][kk] = b01n[nt][kk];
        b23[nt][kk] = b23n[nt][kk];
      }
  }
}

// ---------------- fused QKV GEMM ----------------
__global__ __launch_bounds__(512, 2)
void gemm_qkv_kernel(const unsigned short* __restrict__ xb,
                     const unsigned short* __restrict__ WT,
                     const float* __restrict__ cosT,
                     const float* __restrict__ sinT,
                     unsigned short* __restrict__ Qd,
                     unsigned short* __restrict__ KTd,
                     unsigned short* __restrict__ VTd) {
  __shared__ char lds[131072];
  const int m0 = blockIdx.x * 256;
  const int n0 = blockIdx.y * 256;

  f32x4 acc[8][4];
  #pragma unroll
  for (int i = 0; i < 8; ++i)
    #pragma unroll
    for (int j = 0; j < 4; ++j) acc[i][j] = (f32x4){0.f, 0.f, 0.f, 0.f};

  gemm256_core(xb, WT, m0, n0, lds, acc);

  const int tid = threadIdx.x;
  const int lane = tid & 63;
  const int lrow = lane & 15;
  const int quad = lane >> 4;
  const int wave = tid >> 6;
  const int wm = wave >> 2;
  const int wn = wave & 3;

  const int b = m0 >> 12;
  const int sec = n0 >> 10;          // 0=Q 1=K 2=V (256-wide tile stays in one section)
  const int s0 = (m0 & 4095) + wm * 128;
  const int c0 = (n0 & 1023) + wn * 64;

  if (sec == 2) {
    #pragma unroll
    for (int i = 0; i < 8; ++i) {
      const int sB4 = s0 + i * 16 + quad * 4;
      #pragma unroll
      for (int nt = 0; nt < 4; ++nt) {
        const int c = c0 + nt * 16 + lrow;
        const int h = c >> 6, e = c & 63;
        ushort4 pk;
        pk.x = f2b(acc[i][nt][0]); pk.y = f2b(acc[i][nt][1]);
        pk.z = f2b(acc[i][nt][2]); pk.w = f2b(acc[i][nt][3]);
        *(ushort4*)&VTd[((size_t)(b * 16 + h) * 64 + e) * 4096 + sB4] = pk;
      }
    }
  } else {
    #pragma unroll
    for (int i = 0; i < 8; ++i) {
      const int sB4 = s0 + i * 16 + quad * 4;
      #pragma unroll
      for (int nt = 0; nt < 4; ++nt) {
        const int c = c0 + nt * 16 + lrow;
        const int j = (c & 63) >> 1;
        float ov[4];
        #pragma unroll
        for (int r = 0; r < 4; ++r) {
          const float v = acc[i][nt][r];
          const float p = __shfl_xor(v, 1, 64);
          const int s = sB4 + r;
          const float cs = cosT[s * 32 + j];
          const float sn = sinT[s * 32 + j];
          const float tt = (lane & 1) ? p * sn : -p * sn;
          ov[r] = fmaxf(fmaf(v, cs, tt), 0.0f);
        }
        if (sec == 0) {
          const int grow = m0 + wm * 128 + i * 16 + quad * 4;
          #pragma unroll
          for (int r = 0; r < 4; ++r)
            Qd[(size_t)(grow + r) * 1024 + c] = f2b(ov[r]);
        } else {
          const int h = c >> 6, d = c & 63;
          ushort4 pk;
          pk.x = f2b(ov[0]); pk.y = f2b(ov[1]); pk.z = f2b(ov[2]); pk.w = f2b(ov[3]);
          *(ushort4*)&KTd[((size_t)(b * 16 + h) * 64 + d) * 4096 + sB4] = pk;
        }
      }
    }
  }
}

// ---------------- vk = V_pad^T @ K  (per b,h; K-split partials) ----------------
__global__ __launch_bounds__(256)
void vk_partial_kernel(const unsigned short* __restrict__ KTd,
                       const unsigned short* __restrict__ VTd,
                       float* __restrict__ vkp) {
  __shared__ char sV[4096];
  __shared__ char sK[4096];
  const int tid = threadIdx.x;
  const int lane = tid & 63;
  const int wave = tid >> 6;
  const int lrow = lane & 15;
  const int quad = lane >> 4;
  const int bh = blockIdx.x;
  const int kb = blockIdx.y;
  const int s00 = kb * 512;

  const f32x4 zf = {0.f, 0.f, 0.f, 0.f};
  f32x4 acc[5];
  #pragma unroll
  for (int i = 0; i < 5; i++) acc[i] = zf;

  bf16x8 af4;
  const short oneb = (short)0x3F80;
  #pragma unroll
  for (int j = 0; j < 8; j++) af4[j] = (lrow == 0) ? oneb : (short)0;

  const int srow = tid >> 2;
  const int gcol = ((tid & 3) ^ (srow & 3)) * 8;

  for (int kt = 0; kt < 512; kt += 32) {
    __syncthreads();
    async16(VTd + ((size_t)bh * 64 + srow) * 4096 + s00 + kt + gcol, &sV[tid * 16]);
    async16(KTd + ((size_t)bh * 64 + srow) * 4096 + s00 + kt + gcol, &sK[tid * 16]);
    __syncthreads();
    const int rowK = wave * 16 + lrow;
    bf16x8 bfrag = *(const bf16x8*)&sK[rowK * 64 + ((quad ^ (rowK & 3)) << 4)];
    #pragma unroll
    for (int mt = 0; mt < 4; mt++) {
      const int rowV = mt * 16 + lrow;
      bf16x8 af = *(const bf16x8*)&sV[rowV * 64 + ((quad ^ (rowV & 3)) << 4)];
      acc[mt] = __builtin_amdgcn_mfma_f32_16x16x32_bf16(af, bfrag, acc[mt], 0, 0, 0);
    }
    acc[4] = __builtin_amdgcn_mfma_f32_16x16x32_bf16(af4, bfrag, acc[4], 0, 0, 0);
  }

  #pragma unroll
  for (int mt = 0; mt < 5; mt++) {
    #pragma unroll
    for (int r = 0; r < 4; r++) {
      const int e = mt * 16 + quad * 4 + r;
      const int d = wave * 16 + lrow;
      vkp[((size_t)(bh * 8 + kb) * 80 + e) * 64 + d] = acc[mt][r];
    }
  }
}

__global__ void vk_reduce_kernel(const float* __restrict__ vkp, unsigned short* __restrict__ vkb) {
  int idx = blockIdx.x * 256 + threadIdx.x;
  if (idx >= 64 * 80 * 64) return;
  int bh = idx / 5120, r = idx % 5120;
  float s = 0.f;
  #pragma unroll
  for (int kb = 0; kb < 8; kb++) s += vkp[(size_t)(bh * 8 + kb) * 5120 + r];
  vkb[idx] = f2b(s);
}

// ---------------- num + divide -> attn ----------------
__global__ __launch_bounds__(256)
void attn_kernel(const unsigned short* __restrict__ Qd,
                 const unsigned short* __restrict__ vkb,
                 unsigned short* __restrict__ attn) {
  __shared__ char sQ[32768];
  __shared__ char sVK[10240];
  const int tid = threadIdx.x;
  const int lane = tid & 63;
  const int wave = tid >> 6;
  const int lrow = lane & 15;
  const int quad = lane >> 4;
  const int bh = blockIdx.y, b = bh >> 4, h = bh & 15;
  const int l0 = b * 4096 + blockIdx.x * 256;

  const int c4 = tid & 7;
  #pragma unroll
  for (int r = 0; r < 8; r++) {
    const int o = r * 4096 + tid * 16;
    const int row = o >> 7;
    const int g4 = c4 ^ (row & 7);
    async16(Qd + (size_t)(l0 + row) * 1024 + h * 64 + g4 * 8, &sQ[o]);
  }
  {
    int row = tid >> 3;
    int g4 = c4 ^ (row & 7);
    async16(vkb + (size_t)bh * 5120 + row * 64 + g4 * 8, &sVK[tid * 16]);
    row += 32; g4 = c4 ^ (row & 7);
    async16(vkb + (size_t)bh * 5120 + row * 64 + g4 * 8, &sVK[4096 + tid * 16]);
    if (tid < 128) {
      row = 64 + (tid >> 3); g4 = c4 ^ (row & 7);
      async16(vkb + (size_t)bh * 5120 + row * 64 + g4 * 8, &sVK[8192 + tid * 16]);
    }
  }
  __syncthreads();

  const f32x4 zf = {0.f, 0.f, 0.f, 0.f};
  f32x4 acc[4][5];
  #pragma unroll
  for (int i = 0; i < 4; i++)
    #pragma unroll
    for (int j = 0; j < 5; j++) acc[i][j] = zf;

  #pragma unroll
  for (int kk = 0; kk < 2; kk++) {
    const int kc = kk * 4 + quad;
    bf16x8 af[4], bfr[5];
    #pragma unroll
    for (int mt = 0; mt < 4; mt++) {
      const int row = wave * 64 + mt * 16 + lrow;
      af[mt] = *(const bf16x8*)&sQ[row * 128 + ((kc ^ (row & 7)) << 4)];
    }
    #pragma unroll
    for (int nt = 0; nt < 5; nt++) {
      const int row = nt * 16 + lrow;
      bfr[nt] = *(const bf16x8*)&sVK[row * 128 + ((kc ^ (row & 7)) << 4)];
    }
    #pragma unroll
    for (int mt = 0; mt < 4; mt++)
      #pragma unroll
      for (int nt = 0; nt < 5; nt++)
        acc[mt][nt] = __builtin_amdgcn_mfma_f32_16x16x32_bf16(af[mt], bfr[nt], acc[mt][nt], 0, 0, 0);
  }

  #pragma unroll
  for (int mt = 0; mt < 4; mt++) {
    #pragma unroll
    for (int r = 0; r < 4; r++) {
      const float den = __shfl(acc[mt][4][r], lane & 48, 64);
      const float inv = 1.0f / (den + 1e-6f);
      const int l = l0 + wave * 64 + mt * 16 + quad * 4 + r;
      #pragma unroll
      for (int nt = 0; nt < 4; nt++)
        attn[(size_t)l * 1024 + h * 64 + nt * 16 + lrow] = f2b(acc[mt][nt][r] * inv);
    }
  }
}

// ---------------- out = attn @ Wo : same pipelined core, f32 epilogue ----------------
__global__ __launch_bounds__(512, 2)
void gemm_out_kernel(const unsigned short* __restrict__ A,
                     const unsigned short* __restrict__ BT,
                     float* __restrict__ C) {
  __shared__ char lds[131072];
  const int m0 = blockIdx.x * 256;
  const int n0 = blockIdx.y * 256;

  f32x4 acc[8][4];
  #pragma unroll
  for (int i = 0; i < 8; ++i)
    #pragma unroll
    for (int j = 0; j < 4; ++j) acc[i][j] = (f32x4){0.f, 0.f, 0.f, 0.f};

  gemm256_core(A, BT, m0, n0, lds, acc);

  const int tid = threadIdx.x;
  const int lane = tid & 63;
  const int lrow = lane & 15;
  const int quad = lane >> 4;
  const int wave = tid >> 6;
  const int wm = wave >> 2;
  const int wn = wave & 3;

  const int grow = m0 + wm * 128;
  #pragma unroll
  for (int i = 0; i < 8; ++i) {
    #pragma unroll
    for (int nt = 0; nt < 4; ++nt) {
      const int c = n0 + wn * 64 + nt * 16 + lrow;
      #pragma unroll
      for (int r = 0; r < 4; ++r)
        C[(size_t)(grow + i * 16 + quad * 4 + r) * 1024 + c] = acc[i][nt][r];
    }
  }
}

extern "C" void kernel_launch(void* const* d_in, const int* in_sizes, int n_in,
                              void* d_out, int out_size, void* d_ws, size_t ws_size,
                              hipStream_t stream) {
  const float* x  = (const float*)d_in[0];
  const float* Wq = (const float*)d_in[1];
  const float* Wk = (const float*)d_in[2];
  const float* Wv = (const float*)d_in[3];
  const float* Wo = (const float*)d_in[4];
  float* out = (float*)d_out;

  char* ws = (char*)d_ws;
  size_t off = 0;
  auto alloc = [&](size_t bytes) -> char* {
    char* p = ws + off;
    off += (bytes + 255) & ~(size_t)255;
    return p;
  };

  unsigned short* xb    = (unsigned short*)alloc((size_t)16384 * 1024 * 2);
  unsigned short* WcatT = (unsigned short*)alloc((size_t)3072 * 1024 * 2);
  unsigned short* WoT   = (unsigned short*)alloc((size_t)1024 * 1024 * 2);
  float* cosT           = (float*)alloc((size_t)4096 * 32 * 4);
  float* sinT           = (float*)alloc((size_t)4096 * 32 * 4);
  unsigned short* Qd    = (unsigned short*)alloc((size_t)16384 * 1024 * 2);
  unsigned short* KTd   = (unsigned short*)alloc((size_t)64 * 64 * 4096 * 2);
  unsigned short* VTd   = (unsigned short*)alloc((size_t)64 * 64 * 4096 * 2);
  float* vkp            = (float*)alloc((size_t)512 * 5120 * 4);
  unsigned short* vkb   = (unsigned short*)alloc((size_t)64 * 5120 * 2);
  unsigned short* attn  = xb; // xb dead after gemm_qkv

  prep_kernel<<<16384 + 512 + 4096, 256, 0, stream>>>(x, Wq, Wk, Wv, Wo, xb, WcatT, WoT, cosT, sinT);
  gemm_qkv_kernel<<<dim3(64, 12), 512, 0, stream>>>(xb, WcatT, cosT, sinT, Qd, KTd, VTd);
  vk_partial_kernel<<<dim3(64, 8), 256, 0, stream>>>(KTd, VTd, vkp);
  vk_reduce_kernel<<<1280, 256, 0, stream>>>(vkp, vkb);
  attn_kernel<<<dim3(16, 64), 256, 0, stream>>>(Qd, vkb, attn);
  gemm_out_kernel<<<dim3(64, 4), 512, 0, stream>>>(attn, WoT, out);
}

// Round 4
// 326.511 us; speedup vs baseline: 1.7987x; 1.7987x over previous
//
#include <hip/hip_runtime.h>
#include <stdint.h>

#define GLOBAL_AS __attribute__((address_space(1)))
#define LDS_AS __attribute__((address_space(3)))

typedef float f32x4 __attribute__((ext_vector_type(4)));
typedef short bf16x8 __attribute__((ext_vector_type(8)));

static __device__ __forceinline__ unsigned short f2b(float f) {
  union { float f; unsigned u; } v; v.f = f;
  return (unsigned short)((v.u + 0x7FFFu + ((v.u >> 16) & 1u)) >> 16);
}

static __device__ __forceinline__ void async16(const void* g, void* l) {
  __builtin_amdgcn_global_load_lds((const GLOBAL_AS unsigned int*)g,
                                   (LDS_AS unsigned int*)l, 16, 0, 0);
}

#define BAR() do { __builtin_amdgcn_s_barrier(); __builtin_amdgcn_sched_barrier(0); } while (0)

// ---------------- fused prep: cast_x | rope table | 4x transpose-cast ----------------
__global__ void prep_kernel(const float* __restrict__ x,
                            const float* __restrict__ Wq, const float* __restrict__ Wk,
                            const float* __restrict__ Wv, const float* __restrict__ Wo,
                            unsigned short* __restrict__ xb,
                            unsigned short* __restrict__ WcatT, unsigned short* __restrict__ WoT,
                            float* __restrict__ cosT, float* __restrict__ sinT) {
  __shared__ float tile[32][33];
  const int bid = blockIdx.x;
  const int tid = threadIdx.x;
  if (bid < 16384) {
    const int i = bid * 256 + tid;
    float4 v = ((const float4*)x)[i];
    ushort4 o;
    o.x = f2b(v.x); o.y = f2b(v.y); o.z = f2b(v.z); o.w = f2b(v.w);
    ((ushort4*)xb)[i] = o;
  } else if (bid < 16384 + 512) {
    const int idx = (bid - 16384) * 256 + tid;
    const int s = idx >> 5, j = idx & 31;
    float freq = expf(-((float)(2 * j) * (1.0f / 64.0f)) * 9.210340371976184f);
    float ang = (float)s * freq;
    float sn, cs;
    sincosf(ang, &sn, &cs);
    cosT[idx] = cs;
    sinT[idx] = sn;
  } else {
    const int t = bid - 16896;
    const int mat = t >> 10;
    const int r = t & 1023;
    const int k0 = (r & 31) * 32, n0 = (r >> 5) * 32;
    const float* W = (mat == 0) ? Wq : (mat == 1) ? Wk : (mat == 2) ? Wv : Wo;
    unsigned short* WT = (mat < 3) ? (WcatT + (size_t)mat * 1024 * 1024) : WoT;
    const int tx = tid & 31, ty = tid >> 5;
    #pragma unroll
    for (int i = 0; i < 4; i++)
      tile[ty + i * 8][tx] = W[(size_t)(k0 + ty + i * 8) * 1024 + n0 + tx];
    __syncthreads();
    #pragma unroll
    for (int i = 0; i < 4; i++)
      WT[(size_t)(n0 + ty + i * 8) * 1024 + k0 + tx] = f2b(tile[tx][ty + i * 8]);
  }
}

// ---------------- 256x256x(K=1024) 8-phase core, register-neutral read pipeline ----------------
// 512 thr / 8 waves (2M x 4N), wave tile 128x64, acc[8][4] (128 AGPR). BK=64.
// LDS: 2 dbuf x {A0,A1,B0,B1} 128x64-bf16 half-tiles (16KB each) = 128KB.
// Round-3 post-mortem: full fragment double-buffering demanded ~128 arch VGPRs of fragments
// -> spilled 1GB to scratch under the 128-arch cap. Fix: quadrant order chosen so EVERY
// ds_read targets registers that DIED in the previous phase (no set doubled):
//   ph1: read aq1(t)[8]   | MFMA aq0 x b01 -> acc[0..3][0..1]
//   ph2: read b23(t)[4]   | MFMA aq1 x b01 -> acc[4..7][0..1]   (b01 dead after)
//   ph3: read b01(t+1)[4] | MFMA aq0 x b23 -> acc[0..3][2..3]   (aq0 dead after)
//   ph4: read aq0(t+1)[8] | MFMA aq1 x b23 -> acc[4..7][2..3]   (aq1,b23 dead after)
// Fragments: 32+32+16+16 = 96 arch VGPRs. Reads balanced 8/4/4/8, each issued one full
// MFMA-cluster before its consumer (compiler emits counted lgkmcnt, preserving read-ahead).
// Stage/wait skeleton identical to round 3 (correctness-verified):
//   stages: ph1 A0(t+1)->nxt, ph2 A1(t+1)->nxt, ph3 B0(t+2)->cur, ph4 B1(t+2)->cur
//   waits: ph2 vmcnt(4) drains B(t+1) (read ph3); ph3 vmcnt(2) drains A(t+1) (read ph4);
//   tails t=14: vmcnt(4)/vmcnt(0); t=15: none. Never 0 in steady state.
__device__ __forceinline__ void gemm256_core(const unsigned short* __restrict__ Ag,
                                             const unsigned short* __restrict__ Bg,
                                             int m0, int n0, char* lds, f32x4 (&acc)[8][4]) {
  const int tid = threadIdx.x;
  const int lane = tid & 63;
  const int lrow = lane & 15;
  const int quad = lane >> 4;
  const int wave = tid >> 6;
  const int wm = wave >> 2;
  const int wn = wave & 3;

  const unsigned short* Ar0 = Ag + (size_t)m0 * 1024;
  const unsigned short* Ar1 = Ag + (size_t)(m0 + 128) * 1024;
  const unsigned short* Br0 = Bg + (size_t)n0 * 1024;
  const unsigned short* Br1 = Bg + (size_t)(n0 + 128) * 1024;

  // half-tile = 128 rows x 64 cols bf16 = 1024 slots of 16B; 2 loads/thread.
  // source-side chunk swizzle (ch ^ row&7), linear LDS dest: LDS[row][c] = G[row][c^(row&7)].
  auto stage = [&](const unsigned short* src, char* dst) {
    #pragma unroll
    for (int l = 0; l < 2; ++l) {
      const int slot = l * 512 + tid;
      const int row = slot >> 3;
      const int ch = (slot & 7) ^ (row & 7);
      async16(src + (size_t)row * 1024 + ch * 8, dst + slot * 16);
    }
  };

  const int br0 = (wn & 1) * 64;

  // prologue: tile0 all 4 halves + tile1 B halves (12 loads); vmcnt(4) -> A(0),B(0) landed.
  stage(Ar0, lds);
  stage(Ar1, lds + 16384);
  stage(Br0, lds + 32768);
  stage(Br1, lds + 49152);
  stage(Br0 + 64, lds + 65536 + 32768);
  stage(Br1 + 64, lds + 65536 + 49152);
  asm volatile("s_waitcnt vmcnt(4)" ::: "memory");
  BAR();

  bf16x8 aq0[4][2], aq1[4][2], b01[2][2], b23[2][2];

  // preload aq0(0) and b01(0) (the operands of tile-0 ph1)
  {
    const char* aB = lds + wm * 16384;
    const char* bB = lds + 32768 + (wn >> 1) * 16384;
    #pragma unroll
    for (int mt = 0; mt < 4; ++mt)
      #pragma unroll
      for (int kk = 0; kk < 2; ++kk) {
        const int r = mt * 16 + lrow;
        const int kc = kk * 4 + quad;
        aq0[mt][kk] = *(const bf16x8*)(aB + r * 128 + ((kc ^ (r & 7)) << 4));
      }
    #pragma unroll
    for (int nt = 0; nt < 2; ++nt)
      #pragma unroll
      for (int kk = 0; kk < 2; ++kk) {
        const int r = br0 + nt * 16 + lrow;
        const int kc = kk * 4 + quad;
        b01[nt][kk] = *(const bf16x8*)(bB + r * 128 + ((kc ^ (r & 7)) << 4));
      }
  }

  #pragma unroll 1
  for (int t = 0; t < 16; ++t) {
    const int kt = t * 64;
    char* cur = lds + ((t & 1) << 16);
    char* nxt = lds + (((t + 1) & 1) << 16);
    const char* aB  = cur + wm * 16384;
    const char* aBn = nxt + wm * 16384;
    const char* bB  = cur + 32768 + (wn >> 1) * 16384;
    const char* bBn = nxt + 32768 + (wn >> 1) * 16384;

    // ---- ph1: read aq1(t); stage A0(t+1); MFMA aq0 x b01
    #pragma unroll
    for (int mt = 0; mt < 4; ++mt)
      #pragma unroll
      for (int kk = 0; kk < 2; ++kk) {
        const int r = 64 + mt * 16 + lrow;
        const int kc = kk * 4 + quad;
        aq1[mt][kk] = *(const bf16x8*)(aB + r * 128 + ((kc ^ (r & 7)) << 4));
      }
    if (t < 15) stage(Ar0 + kt + 64, nxt);
    BAR();
    __builtin_amdgcn_s_setprio(1);
    #pragma unroll
    for (int kk = 0; kk < 2; ++kk)
      #pragma unroll
      for (int nt = 0; nt < 2; ++nt)
        #pragma unroll
        for (int mt = 0; mt < 4; ++mt)
          acc[mt][nt] = __builtin_amdgcn_mfma_f32_16x16x32_bf16(aq0[mt][kk], b01[nt][kk], acc[mt][nt], 0, 0, 0);
    __builtin_amdgcn_s_setprio(0);
    BAR();

    // ---- ph2: read b23(t); stage A1(t+1); vmcnt(4) drains B(t+1); MFMA aq1 x b01 (b01 dies)
    #pragma unroll
    for (int nt = 0; nt < 2; ++nt)
      #pragma unroll
      for (int kk = 0; kk < 2; ++kk) {
        const int r = br0 + (nt + 2) * 16 + lrow;
        const int kc = kk * 4 + quad;
        b23[nt][kk] = *(const bf16x8*)(bB + r * 128 + ((kc ^ (r & 7)) << 4));
      }
    if (t < 15) stage(Ar1 + kt + 64, nxt + 16384);
    if (t < 15) { asm volatile("s_waitcnt vmcnt(4)" ::: "memory"); }
    BAR();
    __builtin_amdgcn_s_setprio(1);
    #pragma unroll
    for (int kk = 0; kk < 2; ++kk)
      #pragma unroll
      for (int nt = 0; nt < 2; ++nt)
        #pragma unroll
        for (int mt = 0; mt < 4; ++mt)
          acc[mt + 4][nt] = __builtin_amdgcn_mfma_f32_16x16x32_bf16(aq1[mt][kk], b01[nt][kk], acc[mt + 4][nt], 0, 0, 0);
    __builtin_amdgcn_s_setprio(0);
    BAR();

    // ---- ph3: read b01(t+1) into dead regs; stage B0(t+2); vmcnt(2) drains A(t+1);
    //      MFMA aq0 x b23 (aq0 dies)
    if (t < 15) {
      #pragma unroll
      for (int nt = 0; nt < 2; ++nt)
        #pragma unroll
        for (int kk = 0; kk < 2; ++kk) {
          const int r = br0 + nt * 16 + lrow;
          const int kc = kk * 4 + quad;
          b01[nt][kk] = *(const bf16x8*)(bBn + r * 128 + ((kc ^ (r & 7)) << 4));
        }
    }
    if (t < 14) stage(Br0 + kt + 128, cur + 32768);
    if (t < 14)      { asm volatile("s_waitcnt vmcnt(2)" ::: "memory"); }
    else if (t == 14){ asm volatile("s_waitcnt vmcnt(0)" ::: "memory"); }
    BAR();
    __builtin_amdgcn_s_setprio(1);
    #pragma unroll
    for (int kk = 0; kk < 2; ++kk)
      #pragma unroll
      for (int nt = 0; nt < 2; ++nt)
        #pragma unroll
        for (int mt = 0; mt < 4; ++mt)
          acc[mt][nt + 2] = __builtin_amdgcn_mfma_f32_16x16x32_bf16(aq0[mt][kk], b23[nt][kk], acc[mt][nt + 2], 0, 0, 0);
    __builtin_amdgcn_s_setprio(0);
    BAR();

    // ---- ph4: read aq0(t+1) into dead regs; stage B1(t+2); MFMA aq1 x b23 (aq1,b23 die)
    if (t < 15) {
      #pragma unroll
      for (int mt = 0; mt < 4; ++mt)
        #pragma unroll
        for (int kk = 0; kk < 2; ++kk) {
          const int r = mt * 16 + lrow;
          const int kc = kk * 4 + quad;
          aq0[mt][kk] = *(const bf16x8*)(aBn + r * 128 + ((kc ^ (r & 7)) << 4));
        }
    }
    if (t < 14) stage(Br1 + kt + 128, cur + 49152);
    BAR();
    __builtin_amdgcn_s_setprio(1);
    #pragma unroll
    for (int kk = 0; kk < 2; ++kk)
      #pragma unroll
      for (int nt = 0; nt < 2; ++nt)
        #pragma unroll
        for (int mt = 0; mt < 4; ++mt)
          acc[mt + 4][nt + 2] = __builtin_amdgcn_mfma_f32_16x16x32_bf16(aq1[mt][kk], b23[nt][kk], acc[mt + 4][nt + 2], 0, 0, 0);
    __builtin_amdgcn_s_setprio(0);
    BAR();
  }
}

// ---------------- fused QKV GEMM ----------------
__global__ __launch_bounds__(512, 2)
void gemm_qkv_kernel(const unsigned short* __restrict__ xb,
                     const unsigned short* __restrict__ WT,
                     const float* __restrict__ cosT,
                     const float* __restrict__ sinT,
                     unsigned short* __restrict__ Qd,
                     unsigned short* __restrict__ KTd,
                     unsigned short* __restrict__ VTd) {
  __shared__ char lds[131072];
  const int m0 = blockIdx.x * 256;
  const int n0 = blockIdx.y * 256;

  f32x4 acc[8][4];
  #pragma unroll
  for (int i = 0; i < 8; ++i)
    #pragma unroll
    for (int j = 0; j < 4; ++j) acc[i][j] = (f32x4){0.f, 0.f, 0.f, 0.f};

  gemm256_core(xb, WT, m0, n0, lds, acc);

  const int tid = threadIdx.x;
  const int lane = tid & 63;
  const int lrow = lane & 15;
  const int quad = lane >> 4;
  const int wave = tid >> 6;
  const int wm = wave >> 2;
  const int wn = wave & 3;

  const int b = m0 >> 12;
  const int sec = n0 >> 10;          // 0=Q 1=K 2=V (256-wide tile stays in one section)
  const int s0 = (m0 & 4095) + wm * 128;
  const int c0 = (n0 & 1023) + wn * 64;

  if (sec == 2) {
    #pragma unroll
    for (int i = 0; i < 8; ++i) {
      const int sB4 = s0 + i * 16 + quad * 4;
      #pragma unroll
      for (int nt = 0; nt < 4; ++nt) {
        const int c = c0 + nt * 16 + lrow;
        const int h = c >> 6, e = c & 63;
        ushort4 pk;
        pk.x = f2b(acc[i][nt][0]); pk.y = f2b(acc[i][nt][1]);
        pk.z = f2b(acc[i][nt][2]); pk.w = f2b(acc[i][nt][3]);
        *(ushort4*)&VTd[((size_t)(b * 16 + h) * 64 + e) * 4096 + sB4] = pk;
      }
    }
  } else {
    #pragma unroll
    for (int i = 0; i < 8; ++i) {
      const int sB4 = s0 + i * 16 + quad * 4;
      #pragma unroll
      for (int nt = 0; nt < 4; ++nt) {
        const int c = c0 + nt * 16 + lrow;
        const int j = (c & 63) >> 1;
        float ov[4];
        #pragma unroll
        for (int r = 0; r < 4; ++r) {
          const float v = acc[i][nt][r];
          const float p = __shfl_xor(v, 1, 64);
          const int s = sB4 + r;
          const float cs = cosT[s * 32 + j];
          const float sn = sinT[s * 32 + j];
          const float tt = (lane & 1) ? p * sn : -p * sn;
          ov[r] = fmaxf(fmaf(v, cs, tt), 0.0f);
        }
        if (sec == 0) {
          const int grow = m0 + wm * 128 + i * 16 + quad * 4;
          #pragma unroll
          for (int r = 0; r < 4; ++r)
            Qd[(size_t)(grow + r) * 1024 + c] = f2b(ov[r]);
        } else {
          const int h = c >> 6, d = c & 63;
          ushort4 pk;
          pk.x = f2b(ov[0]); pk.y = f2b(ov[1]); pk.z = f2b(ov[2]); pk.w = f2b(ov[3]);
          *(ushort4*)&KTd[((size_t)(b * 16 + h) * 64 + d) * 4096 + sB4] = pk;
        }
      }
    }
  }
}

// ---------------- vk = V_pad^T @ K  (per b,h; K-split partials) ----------------
__global__ __launch_bounds__(256)
void vk_partial_kernel(const unsigned short* __restrict__ KTd,
                       const unsigned short* __restrict__ VTd,
                       float* __restrict__ vkp) {
  __shared__ char sV[4096];
  __shared__ char sK[4096];
  const int tid = threadIdx.x;
  const int lane = tid & 63;
  const int wave = tid >> 6;
  const int lrow = lane & 15;
  const int quad = lane >> 4;
  const int bh = blockIdx.x;
  const int kb = blockIdx.y;
  const int s00 = kb * 512;

  const f32x4 zf = {0.f, 0.f, 0.f, 0.f};
  f32x4 acc[5];
  #pragma unroll
  for (int i = 0; i < 5; i++) acc[i] = zf;

  bf16x8 af4;
  const short oneb = (short)0x3F80;
  #pragma unroll
  for (int j = 0; j < 8; j++) af4[j] = (lrow == 0) ? oneb : (short)0;

  const int srow = tid >> 2;
  const int gcol = ((tid & 3) ^ (srow & 3)) * 8;

  for (int kt = 0; kt < 512; kt += 32) {
    __syncthreads();
    async16(VTd + ((size_t)bh * 64 + srow) * 4096 + s00 + kt + gcol, &sV[tid * 16]);
    async16(KTd + ((size_t)bh * 64 + srow) * 4096 + s00 + kt + gcol, &sK[tid * 16]);
    __syncthreads();
    const int rowK = wave * 16 + lrow;
    bf16x8 bfrag = *(const bf16x8*)&sK[rowK * 64 + ((quad ^ (rowK & 3)) << 4)];
    #pragma unroll
    for (int mt = 0; mt < 4; mt++) {
      const int rowV = mt * 16 + lrow;
      bf16x8 af = *(const bf16x8*)&sV[rowV * 64 + ((quad ^ (rowV & 3)) << 4)];
      acc[mt] = __builtin_amdgcn_mfma_f32_16x16x32_bf16(af, bfrag, acc[mt], 0, 0, 0);
    }
    acc[4] = __builtin_amdgcn_mfma_f32_16x16x32_bf16(af4, bfrag, acc[4], 0, 0, 0);
  }

  #pragma unroll
  for (int mt = 0; mt < 5; mt++) {
    #pragma unroll
    for (int r = 0; r < 4; r++) {
      const int e = mt * 16 + quad * 4 + r;
      const int d = wave * 16 + lrow;
      vkp[((size_t)(bh * 8 + kb) * 80 + e) * 64 + d] = acc[mt][r];
    }
  }
}

__global__ void vk_reduce_kernel(const float* __restrict__ vkp, unsigned short* __restrict__ vkb) {
  int idx = blockIdx.x * 256 + threadIdx.x;
  if (idx >= 64 * 80 * 64) return;
  int bh = idx / 5120, r = idx % 5120;
  float s = 0.f;
  #pragma unroll
  for (int kb = 0; kb < 8; kb++) s += vkp[(size_t)(bh * 8 + kb) * 5120 + r];
  vkb[idx] = f2b(s);
}

// ---------------- num + divide -> attn ----------------
__global__ __launch_bounds__(256)
void attn_kernel(const unsigned short* __restrict__ Qd,
                 const unsigned short* __restrict__ vkb,
                 unsigned short* __restrict__ attn) {
  __shared__ char sQ[32768];
  __shared__ char sVK[10240];
  const int tid = threadIdx.x;
  const int lane = tid & 63;
  const int wave = tid >> 6;
  const int lrow = lane & 15;
  const int quad = lane >> 4;
  const int bh = blockIdx.y, b = bh >> 4, h = bh & 15;
  const int l0 = b * 4096 + blockIdx.x * 256;

  const int c4 = tid & 7;
  #pragma unroll
  for (int r = 0; r < 8; r++) {
    const int o = r * 4096 + tid * 16;
    const int row = o >> 7;
    const int g4 = c4 ^ (row & 7);
    async16(Qd + (size_t)(l0 + row) * 1024 + h * 64 + g4 * 8, &sQ[o]);
  }
  {
    int row = tid >> 3;
    int g4 = c4 ^ (row & 7);
    async16(vkb + (size_t)bh * 5120 + row * 64 + g4 * 8, &sVK[tid * 16]);
    row += 32; g4 = c4 ^ (row & 7);
    async16(vkb + (size_t)bh * 5120 + row * 64 + g4 * 8, &sVK[4096 + tid * 16]);
    if (tid < 128) {
      row = 64 + (tid >> 3); g4 = c4 ^ (row & 7);
      async16(vkb + (size_t)bh * 5120 + row * 64 + g4 * 8, &sVK[8192 + tid * 16]);
    }
  }
  __syncthreads();

  const f32x4 zf = {0.f, 0.f, 0.f, 0.f};
  f32x4 acc[4][5];
  #pragma unroll
  for (int i = 0; i < 4; i++)
    #pragma unroll
    for (int j = 0; j < 5; j++) acc[i][j] = zf;

  #pragma unroll
  for (int kk = 0; kk < 2; kk++) {
    const int kc = kk * 4 + quad;
    bf16x8 af[4], bfr[5];
    #pragma unroll
    for (int mt = 0; mt < 4; mt++) {
      const int row = wave * 64 + mt * 16 + lrow;
      af[mt] = *(const bf16x8*)&sQ[row * 128 + ((kc ^ (row & 7)) << 4)];
    }
    #pragma unroll
    for (int nt = 0; nt < 5; nt++) {
      const int row = nt * 16 + lrow;
      bfr[nt] = *(const bf16x8*)&sVK[row * 128 + ((kc ^ (row & 7)) << 4)];
    }
    #pragma unroll
    for (int mt = 0; mt < 4; mt++)
      #pragma unroll
      for (int nt = 0; nt < 5; nt++)
        acc[mt][nt] = __builtin_amdgcn_mfma_f32_16x16x32_bf16(af[mt], bfr[nt], acc[mt][nt], 0, 0, 0);
  }

  #pragma unroll
  for (int mt = 0; mt < 4; mt++) {
    #pragma unroll
    for (int r = 0; r < 4; r++) {
      const float den = __shfl(acc[mt][4][r], lane & 48, 64);
      const float inv = 1.0f / (den + 1e-6f);
      const int l = l0 + wave * 64 + mt * 16 + quad * 4 + r;
      #pragma unroll
      for (int nt = 0; nt < 4; nt++)
        attn[(size_t)l * 1024 + h * 64 + nt * 16 + lrow] = f2b(acc[mt][nt][r] * inv);
    }
  }
}

// ---------------- out = attn @ Wo : same pipelined core, f32 epilogue ----------------
__global__ __launch_bounds__(512, 2)
void gemm_out_kernel(const unsigned short* __restrict__ A,
                     const unsigned short* __restrict__ BT,
                     float* __restrict__ C) {
  __shared__ char lds[131072];
  const int m0 = blockIdx.x * 256;
  const int n0 = blockIdx.y * 256;

  f32x4 acc[8][4];
  #pragma unroll
  for (int i = 0; i < 8; ++i)
    #pragma unroll
    for (int j = 0; j < 4; ++j) acc[i][j] = (f32x4){0.f, 0.f, 0.f, 0.f};

  gemm256_core(A, BT, m0, n0, lds, acc);

  const int tid = threadIdx.x;
  const int lane = tid & 63;
  const int lrow = lane & 15;
  const int quad = lane >> 4;
  const int wave = tid >> 6;
  const int wm = wave >> 2;
  const int wn = wave & 3;

  const int grow = m0 + wm * 128;
  #pragma unroll
  for (int i = 0; i < 8; ++i) {
    #pragma unroll
    for (int nt = 0; nt < 4; ++nt) {
      const int c = n0 + wn * 64 + nt * 16 + lrow;
      #pragma unroll
      for (int r = 0; r < 4; ++r)
        C[(size_t)(grow + i * 16 + quad * 4 + r) * 1024 + c] = acc[i][nt][r];
    }
  }
}

extern "C" void kernel_launch(void* const* d_in, const int* in_sizes, int n_in,
                              void* d_out, int out_size, void* d_ws, size_t ws_size,
                              hipStream_t stream) {
  const float* x  = (const float*)d_in[0];
  const float* Wq = (const float*)d_in[1];
  const float* Wk = (const float*)d_in[2];
  const float* Wv = (const float*)d_in[3];
  const float* Wo = (const float*)d_in[4];
  float* out = (float*)d_out;

  char* ws = (char*)d_ws;
  size_t off = 0;
  auto alloc = [&](size_t bytes) -> char* {
    char* p = ws + off;
    off += (bytes + 255) & ~(size_t)255;
    return p;
  };

  unsigned short* xb    = (unsigned short*)alloc((size_t)16384 * 1024 * 2);
  unsigned short* WcatT = (unsigned short*)alloc((size_t)3072 * 1024 * 2);
  unsigned short* WoT   = (unsigned short*)alloc((size_t)1024 * 1024 * 2);
  float* cosT           = (float*)alloc((size_t)4096 * 32 * 4);
  float* sinT           = (float*)alloc((size_t)4096 * 32 * 4);
  unsigned short* Qd    = (unsigned short*)alloc((size_t)16384 * 1024 * 2);
  unsigned short* KTd   = (unsigned short*)alloc((size_t)64 * 64 * 4096 * 2);
  unsigned short* VTd   = (unsigned short*)alloc((size_t)64 * 64 * 4096 * 2);
  float* vkp            = (float*)alloc((size_t)512 * 5120 * 4);
  unsigned short* vkb   = (unsigned short*)alloc((size_t)64 * 5120 * 2);
  unsigned short* attn  = xb; // xb dead after gemm_qkv

  prep_kernel<<<16384 + 512 + 4096, 256, 0, stream>>>(x, Wq, Wk, Wv, Wo, xb, WcatT, WoT, cosT, sinT);
  gemm_qkv_kernel<<<dim3(64, 12), 512, 0, stream>>>(xb, WcatT, cosT, sinT, Qd, KTd, VTd);
  vk_partial_kernel<<<dim3(64, 8), 256, 0, stream>>>(KTd, VTd, vkp);
  vk_reduce_kernel<<<1280, 256, 0, stream>>>(vkp, vkb);
  attn_kernel<<<dim3(16, 64), 256, 0, stream>>>(Qd, vkb, attn);
  gemm_out_kernel<<<dim3(64, 4), 512, 0, stream>>>(attn, WoT, out);
}